// Round 3
// baseline (26595.648 us; speedup 1.0000x reference)
//
#include <hip/hip_runtime.h>
#include <hip/hip_bf16.h>

#define TOKENS 361
#define CDIM 512
#define NHEAD 8
#define DHEAD 64
#define MLPDIM 2048
#define BATCH 256
#define NTOK (BATCH * TOKENS) /* 92416 */
#define HTOK (NTOK / 2)       /* 46208 = 361*128 */
#define SPAN 37

typedef unsigned int uint32;

typedef __attribute__((ext_vector_type(8))) short bf16x8;
typedef __attribute__((ext_vector_type(4))) float f32x4;

__device__ __forceinline__ unsigned short f2bfu(float f) {
  union { float f; uint32 i; } c; c.f = f;
  uint32 i = c.i;
  uint32 r = (i + 0x7fffu + ((i >> 16) & 1u)) >> 16;
  return (unsigned short)r;
}
__device__ __forceinline__ float bfu2f(unsigned short u) {
  union { uint32 i; float f; } c; c.i = ((uint32)u) << 16; return c.f;
}
__device__ __forceinline__ float lo2f(uint32 u) {
  union { uint32 i; float f; } c; c.i = u << 16; return c.f;
}
__device__ __forceinline__ float hi2f(uint32 u) {
  union { uint32 i; float f; } c; c.i = u & 0xffff0000u; return c.f;
}

// ------------------------------------------------- transpose + fp32->bf16
// in fp32 [R, Cc] -> out bf16 [Cc, R]
__global__ __launch_bounds__(256) void transpose_conv(
    const float* __restrict__ in, unsigned short* __restrict__ out, int R, int Cc) {
  __shared__ float tile[32][33];
  int c0 = blockIdx.x * 32, r0 = blockIdx.y * 32;
  int tx = threadIdx.x & 31, ty = threadIdx.x >> 5;
#pragma unroll
  for (int i = 0; i < 32; i += 8)
    tile[ty + i][tx] = in[(size_t)(r0 + ty + i) * Cc + c0 + tx];
  __syncthreads();
#pragma unroll
  for (int i = 0; i < 32; i += 8)
    out[(size_t)(c0 + ty + i) * R + r0 + tx] = f2bfu(tile[tx][ty + i]);
}

// ------------------------------------------------- fused LayerNorm fp32 -> bf16
// one wave per token (512 elems, 8/lane)
__global__ __launch_bounds__(256) void ln_f32(
    const float* __restrict__ x, const float* __restrict__ sc,
    const float* __restrict__ bs, unsigned short* __restrict__ y) {
  int token = blockIdx.x * 4 + (threadIdx.x >> 6);
  int lane = threadIdx.x & 63;
  const float4* xp = (const float4*)(x + (size_t)token * CDIM + lane * 8);
  float4 f0 = xp[0], f1 = xp[1];
  float v[8] = {f0.x, f0.y, f0.z, f0.w, f1.x, f1.y, f1.z, f1.w};
  float sum = 0.f, sumsq = 0.f;
#pragma unroll
  for (int j = 0; j < 8; ++j) { sum += v[j]; sumsq += v[j] * v[j]; }
#pragma unroll
  for (int off = 1; off < 64; off <<= 1) {
    sum += __shfl_xor(sum, off);
    sumsq += __shfl_xor(sumsq, off);
  }
  float mu = sum * (1.f / 512.f);
  float var = sumsq * (1.f / 512.f) - mu * mu;
  float rs = rsqrtf(var + 1e-6f);
  const float4* sp = (const float4*)(sc + lane * 8);
  const float4* bp = (const float4*)(bs + lane * 8);
  float4 s0 = sp[0], s1 = sp[1], b0 = bp[0], b1 = bp[1];
  float sv[8] = {s0.x, s0.y, s0.z, s0.w, s1.x, s1.y, s1.z, s1.w};
  float bv[8] = {b0.x, b0.y, b0.z, b0.w, b1.x, b1.y, b1.z, b1.w};
  uint32 ov[4];
#pragma unroll
  for (int j = 0; j < 4; ++j) {
    float o0 = (v[2 * j] - mu) * rs * sv[2 * j] + bv[2 * j];
    float o1 = (v[2 * j + 1] - mu) * rs * sv[2 * j + 1] + bv[2 * j + 1];
    ov[j] = (uint32)f2bfu(o0) | ((uint32)f2bfu(o1) << 16);
  }
  uint4 outv = {ov[0], ov[1], ov[2], ov[3]};
  *(uint4*)(y + (size_t)token * CDIM + lane * 8) = outv;
}

// ------------------------------------------------- fused LayerNorm bf16 -> bf16
__global__ __launch_bounds__(256) void ln_bf16(
    const unsigned short* __restrict__ x, const float* __restrict__ sc,
    const float* __restrict__ bs, unsigned short* __restrict__ y) {
  int token = blockIdx.x * 4 + (threadIdx.x >> 6);
  int lane = threadIdx.x & 63;
  uint4 pk = *(const uint4*)(x + (size_t)token * CDIM + lane * 8);
  uint32 uu[4] = {pk.x, pk.y, pk.z, pk.w};
  float v[8];
#pragma unroll
  for (int j = 0; j < 4; ++j) { v[2 * j] = lo2f(uu[j]); v[2 * j + 1] = hi2f(uu[j]); }
  float sum = 0.f, sumsq = 0.f;
#pragma unroll
  for (int j = 0; j < 8; ++j) { sum += v[j]; sumsq += v[j] * v[j]; }
#pragma unroll
  for (int off = 1; off < 64; off <<= 1) {
    sum += __shfl_xor(sum, off);
    sumsq += __shfl_xor(sumsq, off);
  }
  float mu = sum * (1.f / 512.f);
  float var = sumsq * (1.f / 512.f) - mu * mu;
  float rs = rsqrtf(var + 1e-6f);
  const float4* sp = (const float4*)(sc + lane * 8);
  const float4* bp = (const float4*)(bs + lane * 8);
  float4 s0 = sp[0], s1 = sp[1], b0 = bp[0], b1 = bp[1];
  float sv[8] = {s0.x, s0.y, s0.z, s0.w, s1.x, s1.y, s1.z, s1.w};
  float bv[8] = {b0.x, b0.y, b0.z, b0.w, b1.x, b1.y, b1.z, b1.w};
  uint32 ov[4];
#pragma unroll
  for (int j = 0; j < 4; ++j) {
    float o0 = (v[2 * j] - mu) * rs * sv[2 * j] + bv[2 * j];
    float o1 = (v[2 * j + 1] - mu) * rs * sv[2 * j + 1] + bv[2 * j + 1];
    ov[j] = (uint32)f2bfu(o0) | ((uint32)f2bfu(o1) << 16);
  }
  uint4 outv = {ov[0], ov[1], ov[2], ov[3]};
  *(uint4*)(y + (size_t)token * CDIM + lane * 8) = outv;
}

__device__ __forceinline__ float gelu_tanh(float u) {
  float c2 = 0.7978845608028654f * (u + 0.044715f * u * u * u);
  float e = __expf(2.f * c2);
  float th = 1.f - 2.f / (e + 1.f);
  return 0.5f * u * (1.f + th);
}

// ------------------------------------------------- GEMM (B^T), bf16 MFMA
// C[M,N] = A[M,K] @ B + bias (+epilogue). BT is [N,K] bf16. bias fp32.
// EPI 0: store bf16. EPI 1: gelu, store bf16.
// EPI 2: += resf (fp32), store bf16. EPI 3: += resb (bf16), store fp32.
#define LSTR 40
template <int EPI>
__global__ __launch_bounds__(256) void gemm_bt(
    const unsigned short* __restrict__ A, const unsigned short* __restrict__ BT,
    const float* __restrict__ bias, const float* __restrict__ resf,
    const unsigned short* __restrict__ resb, void* __restrict__ Cc,
    int M, int N, int K) {
  __shared__ unsigned short As[128 * LSTR];
  __shared__ unsigned short Bs[128 * LSTR];
  int tid = threadIdx.x;
  int wave = tid >> 6, lane = tid & 63;
  int quad = lane >> 4, l16 = lane & 15;
  int m0 = blockIdx.x * 128, n0 = blockIdx.y * 128;
  int wm = (wave >> 1) * 64, wn = (wave & 1) * 64;

  f32x4 acc[4][4];
#pragma unroll
  for (int i = 0; i < 4; ++i)
#pragma unroll
    for (int j = 0; j < 4; ++j) acc[i][j] = (f32x4){0.f, 0.f, 0.f, 0.f};

  int rA = tid >> 2;
  int kc = (tid & 3) * 8;
  const unsigned short* Ap = A + (size_t)(m0 + rA) * K + kc;
  const unsigned short* Ap2 = A + (size_t)(m0 + rA + 64) * K + kc;
  const unsigned short* Bp = BT + (size_t)(n0 + rA) * K + kc;
  const unsigned short* Bp2 = BT + (size_t)(n0 + rA + 64) * K + kc;
  unsigned short* Asw = &As[rA * LSTR + kc];
  unsigned short* Bsw = &Bs[rA * LSTR + kc];

  for (int k0 = 0; k0 < K; k0 += 32) {
    uint4 a0 = *(const uint4*)(Ap + k0);
    uint4 a1 = *(const uint4*)(Ap2 + k0);
    uint4 b0 = *(const uint4*)(Bp + k0);
    uint4 b1 = *(const uint4*)(Bp2 + k0);
    __syncthreads();
    *(uint4*)Asw = a0;
    *(uint4*)(Asw + 64 * LSTR) = a1;
    *(uint4*)Bsw = b0;
    *(uint4*)(Bsw + 64 * LSTR) = b1;
    __syncthreads();
    bf16x8 af[4], bfr[4];
#pragma unroll
    for (int mi = 0; mi < 4; ++mi)
      af[mi] = *(const bf16x8*)&As[(wm + mi * 16 + l16) * LSTR + quad * 8];
#pragma unroll
    for (int ni = 0; ni < 4; ++ni)
      bfr[ni] = *(const bf16x8*)&Bs[(wn + ni * 16 + l16) * LSTR + quad * 8];
#pragma unroll
    for (int mi = 0; mi < 4; ++mi)
#pragma unroll
      for (int ni = 0; ni < 4; ++ni)
        acc[mi][ni] = __builtin_amdgcn_mfma_f32_16x16x32_bf16(af[mi], bfr[ni], acc[mi][ni], 0, 0, 0);
  }

  unsigned short* o16 = (unsigned short*)Cc;
  float* o32 = (float*)Cc;
#pragma unroll
  for (int ni = 0; ni < 4; ++ni) {
    int gc = n0 + wn + ni * 16 + l16;
    float bz = bias[gc];
#pragma unroll
    for (int mi = 0; mi < 4; ++mi) {
#pragma unroll
      for (int r = 0; r < 4; ++r) {
        int gr = m0 + wm + mi * 16 + quad * 4 + r;
        float val = acc[mi][ni][r] + bz;
        if (EPI == 1) val = gelu_tanh(val);
        if (EPI == 2) val += resf[(size_t)gr * N + gc];
        if (EPI == 3) val += bfu2f(resb[(size_t)gr * N + gc]);
        if (EPI == 3) o32[(size_t)gr * N + gc] = val;
        else o16[(size_t)gr * N + gc] = f2bfu(val);
      }
    }
  }
}

// ------------------------------------------------- Attention
// one block per (b_local, h); K in LDS; p broadcast via shuffle; V from L1/L2.
__global__ __launch_bounds__(256) void attn_kernel(
    const unsigned short* __restrict__ q, const unsigned short* __restrict__ k,
    const unsigned short* __restrict__ v, const float* __restrict__ relb,
    unsigned short* __restrict__ ctx) {
  __shared__ unsigned short Ks[TOKENS * 66];
  __shared__ float biasF[1369];
  int b = blockIdx.x >> 3, h = blockIdx.x & 7;
  int tid = threadIdx.x, wave = tid >> 6, lane = tid & 63;
  size_t base = ((size_t)b * TOKENS) * CDIM + h * DHEAD;

  for (int vv = tid; vv < TOKENS * 8; vv += 256) {
    int r = vv >> 3, c = (vv & 7) * 8;
    uint4 pk = *(const uint4*)(k + base + (size_t)r * CDIM + c);
    uint32* dst = (uint32*)&Ks[r * 66 + c];
    dst[0] = pk.x; dst[1] = pk.y; dst[2] = pk.z; dst[3] = pk.w;
  }
  for (int i = tid; i < 1369; i += 256) biasF[i] = relb[h * 1369 + i];
  __syncthreads();

  for (int t = wave; t < TOKENS; t += 4) {
    const uint32* qp = (const uint32*)(q + base + (size_t)t * CDIM);
    float qf[64];
#pragma unroll
    for (int j = 0; j < 32; ++j) {
      uint32 u = qp[j];
      qf[2 * j] = lo2f(u);
      qf[2 * j + 1] = hi2f(u);
    }
    int rt = t / 19, ct2 = t % 19;
    float scv[6];
    float m = -1e30f;
#pragma unroll
    for (int i = 0; i < 6; ++i) {
      int s = lane + (i << 6);
      float scr = -1e30f;
      if (s < TOKENS) {
        const uint32* kr = (const uint32*)&Ks[s * 66];
        float a = 0.f;
#pragma unroll
        for (int j = 0; j < 32; ++j) {
          uint32 u = kr[j];
          a += qf[2 * j] * lo2f(u) + qf[2 * j + 1] * hi2f(u);
        }
        int rs_ = s / 19, cs = s % 19;
        int idx = (rt - rs_ + 18) * SPAN + (ct2 - cs + 18);
        scr = a * 0.125f + biasF[idx];
      }
      scv[i] = scr;
      m = fmaxf(m, scr);
    }
#pragma unroll
    for (int off = 1; off < 64; off <<= 1) m = fmaxf(m, __shfl_xor(m, off));
    float pv[6];
    float sum = 0.f;
#pragma unroll
    for (int i = 0; i < 6; ++i) {
      int s = lane + (i << 6);
      float p = (s < TOKENS) ? __expf(scv[i] - m) : 0.f;
      pv[i] = p;
      sum += p;
    }
#pragma unroll
    for (int off = 1; off < 64; off <<= 1) sum += __shfl_xor(sum, off);
    float inv = 1.f / sum;

    const unsigned short* vp = v + base + lane;
    float a = 0.f;
#pragma unroll
    for (int i = 0; i < 5; ++i) {
      for (int j = 0; j < 64; ++j)
        a += __shfl(pv[i], j) * bfu2f(vp[(size_t)((i << 6) + j) * CDIM]);
    }
    for (int j = 0; j < 41; ++j)
      a += __shfl(pv[5], j) * bfu2f(vp[(size_t)(320 + j) * CDIM]);
    ctx[base + (size_t)t * CDIM + lane] = f2bfu(a * inv);
  }
}

// ------------------------------------------------- launch
extern "C" void kernel_launch(void* const* d_in, const int* in_sizes, int n_in,
                              void* d_out, int out_size, void* d_ws, size_t ws_size,
                              hipStream_t stream) {
  const float* x     = (const float*)d_in[0];
  const float* ln1_s = (const float*)d_in[1];
  const float* ln1_b = (const float*)d_in[2];
  const float* Wq    = (const float*)d_in[3];
  const float* bq    = (const float*)d_in[4];
  const float* Wk    = (const float*)d_in[5];
  const float* bk    = (const float*)d_in[6];
  const float* Wv    = (const float*)d_in[7];
  const float* bv    = (const float*)d_in[8];
  const float* Wo    = (const float*)d_in[9];
  const float* bo    = (const float*)d_in[10];
  const float* relb  = (const float*)d_in[11];
  const float* ln2_s = (const float*)d_in[12];
  const float* ln2_b = (const float*)d_in[13];
  const float* W1    = (const float*)d_in[14];
  const float* b1    = (const float*)d_in[15];
  const float* W2    = (const float*)d_in[16];
  const float* b2    = (const float*)d_in[17];
  float* out = (float*)d_out;

  // ws layout (~367 MB): bf16 weights 6.3 MB | y 94.6 MB | x1b 94.6 MB |
  // q/k/v/ctx half-batch 4x47.3 MB (overlaid by MLP hidden)
  char* ws = (char*)d_ws;
  unsigned short* WqT = (unsigned short*)ws;
  unsigned short* WkT = WqT + 512 * 512;
  unsigned short* WvT = WkT + 512 * 512;
  unsigned short* WoT = WvT + 512 * 512;
  unsigned short* W1T = WoT + 512 * 512;
  unsigned short* W2T = W1T + 512 * 2048;
  unsigned short* yb  = W2T + 2048 * 512;          // NTOK*512 bf16
  unsigned short* x1b = yb + (size_t)NTOK * CDIM;  // NTOK*512 bf16
  unsigned short* qb  = x1b + (size_t)NTOK * CDIM;
  const size_t HS = (size_t)HTOK * CDIM;
  unsigned short* kb   = qb + HS;
  unsigned short* vb   = kb + HS;
  unsigned short* ctxb = vb + HS;
  unsigned short* hdn  = qb;  // HTOK*2048 bf16, overlays q/k/v/ctx

  dim3 blk(256);
  transpose_conv<<<dim3(16, 16), blk, 0, stream>>>(Wq, WqT, 512, 512);
  transpose_conv<<<dim3(16, 16), blk, 0, stream>>>(Wk, WkT, 512, 512);
  transpose_conv<<<dim3(16, 16), blk, 0, stream>>>(Wv, WvT, 512, 512);
  transpose_conv<<<dim3(16, 16), blk, 0, stream>>>(Wo, WoT, 512, 512);
  transpose_conv<<<dim3(64, 16), blk, 0, stream>>>(W1, W1T, 512, 2048);
  transpose_conv<<<dim3(16, 64), blk, 0, stream>>>(W2, W2T, 2048, 512);

  ln_f32<<<NTOK / 4, blk, 0, stream>>>(x, ln1_s, ln1_b, yb);

  for (int c = 0; c < 2; ++c) {
    size_t off = (size_t)c * HTOK;
    const unsigned short* yc = yb + off * CDIM;
    gemm_bt<0><<<dim3(361, 4), blk, 0, stream>>>(yc, WqT, bq, nullptr, nullptr, qb, HTOK, 512, 512);
    gemm_bt<0><<<dim3(361, 4), blk, 0, stream>>>(yc, WkT, bk, nullptr, nullptr, kb, HTOK, 512, 512);
    gemm_bt<0><<<dim3(361, 4), blk, 0, stream>>>(yc, WvT, bv, nullptr, nullptr, vb, HTOK, 512, 512);
    attn_kernel<<<dim3((BATCH / 2) * NHEAD), blk, 0, stream>>>(qb, kb, vb, relb, ctxb);
    gemm_bt<2><<<dim3(361, 4), blk, 0, stream>>>(ctxb, WoT, bo, x + off * CDIM, nullptr,
                                                 x1b + off * CDIM, HTOK, 512, 512);
  }

  ln_bf16<<<NTOK / 4, blk, 0, stream>>>(x1b, ln2_s, ln2_b, yb);

  for (int c = 0; c < 2; ++c) {
    size_t off = (size_t)c * HTOK;
    gemm_bt<1><<<dim3(361, 16), blk, 0, stream>>>(yb + off * CDIM, W1T, b1, nullptr, nullptr,
                                                  hdn, HTOK, 2048, 512);
    gemm_bt<3><<<dim3(361, 4), blk, 0, stream>>>(hdn, W2T, b2, nullptr, x1b + off * CDIM,
                                                 out + off * CDIM, HTOK, 512, 2048);
  }
}